// Round 2
// 409.084 us; speedup vs baseline: 1.0109x; 1.0109x over previous
//
#include <hip/hip_runtime.h>

// STN bilinear sampler: x [32,256,256,32] f32 NHWC, theta [32,6] f32
// out [32,256,256,32] f32.
//
// R1: 420 us with 32x1-pixel blocks. R2/R3: 8x4 tiles + nontemporal stores
// -> 413.5 us. rocprof shows stn_kernel <= 165 us under profiling (all top-5
// dispatches are the harness' 1-GiB poison fills); the bench-time gap is the
// cold-L3 scattered-fetch path.
//
// R4: halve wave count / double MLP. 4 threads per pixel (2 float4 chunks
// each, 8 loads in flight), 8x8 pixel tile, theta read via wave-uniform
// s_load (no LDS, no barrier). fp64 coord chain computed 4x per pixel
// instead of 8x. Expression order kept bit-identical to R3 (truncation
// boundaries must match the fp64 numpy reference).
//
// R5: identical resubmit of R4 — previous round died on container
// acquisition ("MI355X container failed twice"), never measured.

#define B_  32
#define H_  256
#define W_  256
#define C_  32

// tile: 8 px in x, 8 px in y; 4 threads per pixel (each owns 8 channels)
#define TX_ 8
#define TY_ 8

typedef float floatx4 __attribute__((ext_vector_type(4)));

__global__ __launch_bounds__(256) void stn_kernel(
    const float* __restrict__ x,
    const float* __restrict__ theta,
    float* __restrict__ out)
{
    const int tid = threadIdx.x;
    const int v   = tid & 3;          // channel chunk (floats v*8 .. v*8+7)
    const int pxl = tid >> 2;         // 0..63 pixel within tile
    const int tx  = pxl & (TX_ - 1);
    const int ty  = pxl >> 3;

    const int px = blockIdx.x * TX_ + tx;
    const int py = blockIdx.y * TY_ + ty;
    const int b  = blockIdx.z;

    // b is wave-uniform -> these become scalar loads; no LDS broadcast needed
    const double t0 = (double)theta[b * 6 + 0];
    const double t1 = (double)theta[b * 6 + 1];
    const double t2 = (double)theta[b * 6 + 2];
    const double t3 = (double)theta[b * 6 + 3];
    const double t4 = (double)theta[b * 6 + 4];
    const double t5 = (double)theta[b * 6 + 5];

    // numpy: xs[i] = (2.0*i)/255.0 - 1.0
    const double gx = (2.0 * (double)px) / 255.0 - 1.0;
    const double gy = (2.0 * (double)py) / 255.0 - 1.0;

    // einsum order: (t0*gx + t1*gy) + t2   (keep expression shape identical)
    const double sxs = t0 * gx + t1 * gy + t2;
    const double sys = t3 * gx + t4 * gy + t5;

    const double sx = 0.5 * (sxs + 1.0) * (double)W_;
    const double sy = 0.5 * (sys + 1.0) * (double)H_;

    // truncation toward zero, matching astype(int32)
    const int x0 = (int)sx;
    const int y0 = (int)sy;
    const int x1 = x0 + 1;
    const int y1 = y0 + 1;

    const int x0c = min(max(x0, 0), W_ - 1);
    const int x1c = min(max(x1, 0), W_ - 1);
    const int y0c = min(max(y0, 0), H_ - 1);
    const int y1c = min(max(y1, 0), H_ - 1);

    const double x0f = (double)x0c, x1f = (double)x1c;
    const double y0f = (double)y0c, y1f = (double)y1c;

    const float wa = (float)((x1f - sx) * (y1f - sy));
    const float wb = (float)((x1f - sx) * (sy - y0f));
    const float wc = (float)((sx - x0f) * (y1f - sy));
    const float wd = (float)((sx - x0f) * (sy - y0f));

    const long long base = (long long)b * (H_ * W_);
    const float* pax = x + ((base + (long long)(y0c * W_ + x0c)) * C_) + v * 8;
    const float* pbx = x + ((base + (long long)(y1c * W_ + x0c)) * C_) + v * 8;
    const float* pcx = x + ((base + (long long)(y0c * W_ + x1c)) * C_) + v * 8;
    const float* pdx = x + ((base + (long long)(y1c * W_ + x1c)) * C_) + v * 8;

    // 8 independent 16-B loads in flight per thread
    const floatx4 pa0 = *reinterpret_cast<const floatx4*>(pax);
    const floatx4 pa1 = *reinterpret_cast<const floatx4*>(pax + 4);
    const floatx4 pb0 = *reinterpret_cast<const floatx4*>(pbx);
    const floatx4 pb1 = *reinterpret_cast<const floatx4*>(pbx + 4);
    const floatx4 pc0 = *reinterpret_cast<const floatx4*>(pcx);
    const floatx4 pc1 = *reinterpret_cast<const floatx4*>(pcx + 4);
    const floatx4 pd0 = *reinterpret_cast<const floatx4*>(pdx);
    const floatx4 pd1 = *reinterpret_cast<const floatx4*>(pdx + 4);

    floatx4 r0 = wa * pa0 + wb * pb0 + wc * pc0 + wd * pd0;
    floatx4 r1 = wa * pa1 + wb * pb1 + wc * pc1 + wd * pd1;

    const long long po = (long long)((b << 16) | (py << 8) | px);
    float* o = out + po * C_ + v * 8;
    __builtin_nontemporal_store(r0, reinterpret_cast<floatx4*>(o));
    __builtin_nontemporal_store(r1, reinterpret_cast<floatx4*>(o + 4));
}

extern "C" void kernel_launch(void* const* d_in, const int* in_sizes, int n_in,
                              void* d_out, int out_size, void* d_ws, size_t ws_size,
                              hipStream_t stream) {
    const float* x     = (const float*)d_in[0];
    const float* theta = (const float*)d_in[1];
    float* out         = (float*)d_out;

    dim3 grid(W_ / TX_, H_ / TY_, B_);   // 32 x 32 x 32
    dim3 block(256);

    stn_kernel<<<grid, block, 0, stream>>>(x, theta, out);
}